// Round 7
// baseline (246.722 us; speedup 1.0000x reference)
//
#include <hip/hip_runtime.h>

// CANet fused kernel, round 12.
// Post-mortem r11: occupancy 30->39% with zero spill changed NOTHING (140us).
// With r9 (47% occ) this falsifies the occupancy theory: limiter is a per-CU
// shared resource. Per-SIMD VALU ~10%, MFMA ~17%, HBM 13% -> only candidate
// near saturation is the LDS pipe (~66 b128 reads + 20 writes /lane-iter ~=
// 63-86% busy incl 57K conflict cyc/CU). Conv's wpT broadcast reads = 27 of
// those 66, plus conv's serial FMA chain sets the phase critical path.
// r12: fold depthwise conv INTO GEMM1 (both linear):
//   h1 = w1.(DWConv(xf)+bp)+b1 = Wf (*) xf + b1'
//   Wf[o][ic,k] = sum_j w1[o][4ic+j]*wp[4ic+j][k]  (prep, bf16, [128][128])
//   b1' = b1 + w1.bp                               (prep, f32)
// Main kernel conv phase -> pure im2col staging (27 tap loads, mask, pack,
// 16 b32 writes). K layout: 4 q-blocks of 32 = 3 ic x 10 (9 taps + 1 pad) + 2.
// Deletes/lane-iter: 27 wpT reads + 3 bp reads + 108 FMA + conv dep chain.
// Adds: +8 G1 B-reads (K 64->128), +16 MFMA, +16 w1f regs. Net LDS ~ -25%.
// Canaries: FETCH/WRITE jump = spill (abort); absmax shift (rounding moved).

#define ACT_S 136     // 272 B rows (16B-aligned) for bufA/h1S [px][ch]
#define NOISE_BASE 9437184   // 16*9*65536

// d_ws shorts: Wf[128][128]@0, w2[128][128]@16384, w3[16][128]@32768 (2048)
// floats @ WSF_OFF: b1'[128]@0, b2[128]@128, emb[48]@256
#define WSF_OFF 17408
#define WSF_B1 0
#define WSF_B2 128
#define WSF_EMB 256

typedef short bf16x8 __attribute__((ext_vector_type(8)));
typedef float f32x4 __attribute__((ext_vector_type(4)));

__device__ __forceinline__ short f2bf(float f) {
    union { float f; unsigned u; } cv; cv.f = f;
    unsigned r = cv.u + 0x7FFFu + ((cv.u >> 16) & 1u);
    return (short)(r >> 16);
}
// pack two fp32 -> dword of two bf16 (round-half-up): lo16=bf(f0), hi16=bf(f1)
__device__ __forceinline__ unsigned pk2bf(float f0, float f1) {
    union { float f; unsigned u; } a, b; a.f = f0; b.f = f1;
    return __builtin_amdgcn_perm(b.u + 0x8000u, a.u + 0x8000u, 0x07060302u);
}

// ---------------- weight prep (fused Wf/b1') + time embedding ----------------
__global__ void prep_emb_kernel(const float* __restrict__ wpg, const float* __restrict__ bpg,
                                const float* __restrict__ w1g, const float* __restrict__ b1g,
                                const float* __restrict__ w2g, const float* __restrict__ b2g,
                                const float* __restrict__ w3g,
                                const int* __restrict__ t,
                                const float* __restrict__ wt, const float* __restrict__ bt,
                                short* __restrict__ wsb, float* __restrict__ wsf)
{
    const int bid = blockIdx.x, tid = threadIdx.x;
    if (bid < 64) {                       // Wf [128][128]: col = 32q + 10*c3 + k
        int i = bid * 256 + tid;
        int o = i >> 7, kk = i & 127;
        int qq = kk >> 5, r = kk & 31;
        float v = 0.f;
        if (r < 30 && (r % 10) < 9) {
            int c3 = r / 10, k = r % 10;
            int ic = 3 * qq + c3;
            #pragma unroll
            for (int j = 0; j < 4; ++j)
                v += w1g[o * 48 + 4 * ic + j] * wpg[(4 * ic + j) * 9 + k];
        }
        wsb[i] = f2bf(v);
        return;
    }
    if (bid < 128) {                      // w2 [128][128]
        int i = (bid - 64) * 256 + tid;
        wsb[16384 + i] = f2bf(w2g[i]);
        return;
    }
    if (bid == 128) {                     // w3 [12][128] -> [16][128] pad
        for (int j = tid; j < 2048; j += 256)
            wsb[32768 + j] = (j < 1536) ? f2bf(w3g[j]) : (short)0;
        return;
    }
    if (bid == 129) {                     // b1' = b1 + w1.bp ; b2 copy
        if (tid < 128) {
            float s = b1g[tid];
            #pragma unroll 4
            for (int c = 0; c < 48; ++c) s += w1g[tid * 48 + c] * bpg[c];
            wsf[WSF_B1 + tid] = s;
        } else {
            wsf[WSF_B2 + (tid - 128)] = b2g[tid - 128];
        }
        return;
    }
    int b = bid - 130;                    // time embedding, one block per batch
    int lane = threadIdx.x;
    if (lane >= 64) return;
    float tv = (float)t[b];
    float s0 = 0.f, s1 = 0.f, s2 = 0.f;
    const float LOG1E4 = 9.210340371976184f;
    #pragma unroll
    for (int ii = 0; ii < 2; ++ii) {
        int i = lane + ii * 64;
        float invf = __expf(-LOG1E4 * (float)i * (1.0f / 128.0f));
        float ang = tv * invf;
        float sn = sinf(ang), cs = cosf(ang);
        float ss = sn / (1.0f + __expf(-sn));
        float sc = cs / (1.0f + __expf(-cs));
        s0 += ss * wt[0 * 256 + i] + sc * wt[0 * 256 + i + 128];
        s1 += ss * wt[1 * 256 + i] + sc * wt[1 * 256 + i + 128];
        s2 += ss * wt[2 * 256 + i] + sc * wt[2 * 256 + i + 128];
    }
    #pragma unroll
    for (int off = 32; off; off >>= 1) {
        s0 += __shfl_down(s0, off);
        s1 += __shfl_down(s1, off);
        s2 += __shfl_down(s2, off);
    }
    if (lane == 0) {
        wsf[WSF_EMB + b * 3 + 0] = s0 + bt[0];
        wsf[WSF_EMB + b * 3 + 1] = s1 + bt[1];
        wsf[WSF_EMB + b * 3 + 2] = s2 + bt[2];
    }
}

// ---------------- main fused kernel ----------------
// MFMA 16x16x32 (m89): A lane(i=lane&15,q) holds A[i][q*8+j]; B symmetric:
// lane holds B[q*8+j][i]. D: col(N)=lane&15, row(M)=q*4+r.
// bufA timeline per iter: stage im2col (cols 0..127) -> B1 -> G1 reads it,
// writes h1S -> B2 -> G2 reads h1S, writes h2 -> bufA -> B3 -> G3 reads bufA
// -> B4 -> next iter's staging overwrites bufA.
__global__ __launch_bounds__(256, 4) void canet_main(
    const float* __restrict__ xg,   // (16,3,256,256)
    const float* __restrict__ hg,   // (16,9,256,256)
    const short* __restrict__ wsb,
    const float* __restrict__ wsf,
    float* __restrict__ outg)
{
    __shared__ __align__(16) short bufA[64 * ACT_S];   // im2col / h2
    __shared__ __align__(16) short h1S[64 * ACT_S];
    __shared__ __align__(16) short w3_s[12 * 128];     // [oc][k], col XOR-swizzled
    __shared__ __align__(16) float bias_s[256];        // b1' @0, b2 @128

    const int tid = threadIdx.x;
    const int b = blockIdx.x >> 8;
    const int y = blockIdx.x & 255;

    bias_s[tid] = wsf[WSF_B1 + tid];                   // b1'[0:128], b2[128:256]
    for (int i = tid; i < 1536; i += 256) {            // w3 [12][128] swizzled
        int row = i >> 7, col = i & 127;
        w3_s[(row << 7) + (col ^ ((row & 7) << 3))] = wsb[32768 + i];
    }

    const int wv = tid >> 6;
    const int lane = tid & 63;
    const int m = lane & 15;
    const int q = lane >> 4;

    // ---- persistent weight fragments (Wf, w2; 64 regs) ----
    bf16x8 w1f[2][4], w2f[2][4];
    #pragma unroll
    for (int j = 0; j < 2; ++j) {
        int n = wv * 32 + j * 16 + m;
        #pragma unroll
        for (int ks = 0; ks < 4; ++ks) {
            w1f[j][ks] = *(const bf16x8*)(wsb + n * 128 + ks * 32 + q * 8);
            w2f[j][ks] = *(const bf16x8*)(wsb + 16384 + n * 128 + ks * 32 + q * 8);
        }
    }
    const float embv = (m < 3) ? wsf[WSF_EMB + b * 3 + m] : 0.0f;

    // conv source pointers (lane's 3 input channels: ic = 3q + i3)
    const float* src3[3];
    #pragma unroll
    for (int i3 = 0; i3 < 3; ++i3) {
        int ic = 3 * q + i3;
        src3[i3] = (ic < 3) ? (xg + (((size_t)b * 3 + ic) << 16))
                            : (hg + (((size_t)b * 9 + (ic - 3)) << 16));
    }

    const int mm = (m < 12) ? m : 11;        // w3 row clamp (lanes 12-15 discarded)
    const int w3sw = (mm & 7) << 3;

    __syncthreads();   // staged LDS ready

    for (int it = 0; it < 4; ++it) {
        const int x0 = it * 64;
        const int px = x0 + wv * 16 + m;

        // ---- im2col staging: taps -> bf16 -> bufA[px][32q + 10*i3 + k] ----
        {
            const int xm1 = px - (px > 0);
            const int xp1 = px + (px < 255);
            const bool okl = (px > 0), okr = (px < 255);
            short* prow = bufA + (wv * 16 + m) * ACT_S + 32 * q;
            const bool interior = (y >= 1) && (y <= 254);
            #pragma unroll
            for (int i3 = 0; i3 < 3; ++i3) {
                const float* s = src3[i3];
                float tap[9];
                if (interior) {
                    #pragma unroll
                    for (int ky = 0; ky < 3; ++ky) {
                        const float* rp = s + (y + ky - 1) * 256;
                        float c0 = rp[xm1], c1 = rp[px], c2 = rp[xp1];
                        tap[ky * 3 + 0] = okl ? c0 : 0.0f;
                        tap[ky * 3 + 1] = c1;
                        tap[ky * 3 + 2] = okr ? c2 : 0.0f;
                    }
                } else {
                    #pragma unroll
                    for (int ky = 0; ky < 3; ++ky) {
                        int yy = y + ky - 1;
                        bool yok = (yy >= 0) && (yy < 256);
                        const float* rp = s + (yok ? yy : y) * 256;
                        float c0 = rp[xm1], c1 = rp[px], c2 = rp[xp1];
                        tap[ky * 3 + 0] = (yok && okl) ? c0 : 0.0f;
                        tap[ky * 3 + 1] = yok ? c1 : 0.0f;
                        tap[ky * 3 + 2] = (yok && okr) ? c2 : 0.0f;
                    }
                }
                unsigned* pw = (unsigned*)(prow + 10 * i3);   // 4B-aligned (even shorts)
                pw[0] = pk2bf(tap[0], tap[1]);
                pw[1] = pk2bf(tap[2], tap[3]);
                pw[2] = pk2bf(tap[4], tap[5]);
                pw[3] = pk2bf(tap[6], tap[7]);
                pw[4] = pk2bf(tap[8], 0.0f);                  // k=9 pad
            }
            *(unsigned*)(prow + 30) = 0u;                     // q-block pad 30,31
        }
        __syncthreads();   // B1: im2col ready

        // ---- GEMM1 (swapped): D[ch][px] = Wf . im2col^T ; write h1S[px][ch] ----
        #pragma unroll
        for (int nt = 0; nt < 4; ++nt) {
            f32x4 c0 = *(const f32x4*)(bias_s + wv * 32 + q * 4);
            f32x4 c1 = *(const f32x4*)(bias_s + wv * 32 + 16 + q * 4);
            #pragma unroll
            for (int ks = 0; ks < 4; ++ks) {
                bf16x8 p = *(const bf16x8*)(bufA + (nt * 16 + m) * ACT_S + ks * 32 + q * 8);
                c0 = __builtin_amdgcn_mfma_f32_16x16x32_bf16(w1f[0][ks], p, c0, 0, 0, 0);
                c1 = __builtin_amdgcn_mfma_f32_16x16x32_bf16(w1f[1][ks], p, c1, 0, 0, 0);
            }
            short* drow = h1S + (nt * 16 + m) * ACT_S + wv * 32 + q * 4;
            uint2 pk;
            pk.x = pk2bf(fmaxf(c0[0], 0.f), fmaxf(c0[1], 0.f));
            pk.y = pk2bf(fmaxf(c0[2], 0.f), fmaxf(c0[3], 0.f));
            *(uint2*)drow = pk;
            pk.x = pk2bf(fmaxf(c1[0], 0.f), fmaxf(c1[1], 0.f));
            pk.y = pk2bf(fmaxf(c1[2], 0.f), fmaxf(c1[3], 0.f));
            *(uint2*)(drow + 16) = pk;
        }
        __syncthreads();   // B2: h1 ready; im2col fully read

        // ---- GEMM2 (swapped): D[ch][px] = w2 . h1^T ; write h2 -> bufA ----
        #pragma unroll
        for (int nt = 0; nt < 4; ++nt) {
            f32x4 c0 = *(const f32x4*)(bias_s + 128 + wv * 32 + q * 4);
            f32x4 c1 = *(const f32x4*)(bias_s + 128 + wv * 32 + 16 + q * 4);
            #pragma unroll
            for (int ks = 0; ks < 4; ++ks) {
                bf16x8 a = *(const bf16x8*)(h1S + (nt * 16 + m) * ACT_S + ks * 32 + q * 8);
                c0 = __builtin_amdgcn_mfma_f32_16x16x32_bf16(w2f[0][ks], a, c0, 0, 0, 0);
                c1 = __builtin_amdgcn_mfma_f32_16x16x32_bf16(w2f[1][ks], a, c1, 0, 0, 0);
            }
            short* drow = bufA + (nt * 16 + m) * ACT_S + wv * 32 + q * 4;
            uint2 pk;
            pk.x = pk2bf(fmaxf(c0[0], 0.f), fmaxf(c0[1], 0.f));
            pk.y = pk2bf(fmaxf(c0[2], 0.f), fmaxf(c0[3], 0.f));
            *(uint2*)drow = pk;
            pk.x = pk2bf(fmaxf(c1[0], 0.f), fmaxf(c1[1], 0.f));
            pk.y = pk2bf(fmaxf(c1[2], 0.f), fmaxf(c1[3], 0.f));
            *(uint2*)(drow + 16) = pk;
        }
        __syncthreads();   // B3: h2 ready

        // ---- GEMM3: out = h2 . w3^T ; D col=oc, row=px; float4 store ----
        {
            f32x4 acc = {0.f, 0.f, 0.f, 0.f};
            #pragma unroll
            for (int ks = 0; ks < 4; ++ks) {
                bf16x8 a = *(const bf16x8*)(bufA + (wv * 16 + m) * ACT_S + ks * 32 + q * 8);
                bf16x8 w3k = *(const bf16x8*)(w3_s + (mm << 7) + ((ks * 32 + q * 8) ^ w3sw));
                acc = __builtin_amdgcn_mfma_f32_16x16x32_bf16(a, w3k, acc, 0, 0, 0);
            }
            if (m < 12) {
                int xx0 = x0 + wv * 16 + q * 4;
                size_t idx;
                if (m < 3) {
                    idx = (size_t)NOISE_BASE + (((size_t)b * 3 + m) << 16) + (size_t)y * 256 + xx0;
                } else {
                    idx = (((size_t)b * 9 + (m - 3)) << 16) + (size_t)y * 256 + xx0;
                }
                f32x4 vst = {acc[0] + embv, acc[1] + embv, acc[2] + embv, acc[3] + embv};
                *(f32x4*)(outg + idx) = vst;
            }
        }
        __syncthreads();   // B4: bufA fully read; next staging may overwrite
    }
}

extern "C" void kernel_launch(void* const* d_in, const int* in_sizes, int n_in,
                              void* d_out, int out_size, void* d_ws, size_t ws_size,
                              hipStream_t stream) {
    const float* xg  = (const float*)d_in[0];
    const float* hg  = (const float*)d_in[1];
    const int*   tg  = (const int*)  d_in[2];
    const float* wpg = (const float*)d_in[3];
    const float* bpg = (const float*)d_in[4];
    const float* w1g = (const float*)d_in[5];
    const float* b1g = (const float*)d_in[6];
    const float* w2g = (const float*)d_in[7];
    const float* b2g = (const float*)d_in[8];
    const float* w3g = (const float*)d_in[9];
    const float* wtg = (const float*)d_in[10];
    const float* btg = (const float*)d_in[11];
    float* outg = (float*)d_out;
    short* wsb  = (short*)d_ws;
    float* wsf  = (float*)d_ws + WSF_OFF;

    prep_emb_kernel<<<146, 256, 0, stream>>>(wpg, bpg, w1g, b1g, w2g, b2g, w3g,
                                             tg, wtg, btg, wsb, wsf);
    canet_main<<<4096, 256, 0, stream>>>(xg, hg, wsb, wsf, outg);
}

// Round 8
// 219.067 us; speedup vs baseline: 1.1262x; 1.1262x over previous
//
#include <hip/hip_runtime.h>

// CANet fused kernel, round 13.
// Post-mortem r12: spill canary FIRED (WRITE 65.5->122.9MB, FETCH +17MB):
// launch_bounds(256,4) capped total regs at 128 while the conv-fold grew the
// persistent set to ~64 (w1f[2][4]+w2f[2][4]) + taps ~= 140 peak -> scratch.
// Dur 140->158. BUT the fold mechanism worked: VALUBusy 40->30 (conv chain
// gone), MfmaUtil 16.5->19. And r9/r11 proved occupancy 30 vs 47% is
// perf-NEUTRAL here, so the 4-block bound buys nothing and costs spill.
// r13 = r12 with ONE change: __launch_bounds__(256,3) -> reg cap ~170, no
// spill, occupancy back to ~30% (irrelevant). Clean A/B of conv-fold vs
// r5/r10's 139us at equal no-spill conditions.
// Canaries: WRITE ~65.5MB & FETCH ~76MB restored = spill gone. Dur <135 =
// fold wins; >=140 = fold neutral -> revert & attack LDS pipe (32x32 MFMA).

#define ACT_S 136     // 272 B rows (16B-aligned) for bufA/h1S [px][ch]
#define NOISE_BASE 9437184   // 16*9*65536

// d_ws shorts: Wf[128][128]@0, w2[128][128]@16384, w3[16][128]@32768 (2048)
// floats @ WSF_OFF: b1'[128]@0, b2[128]@128, emb[48]@256
#define WSF_OFF 17408
#define WSF_B1 0
#define WSF_B2 128
#define WSF_EMB 256

typedef short bf16x8 __attribute__((ext_vector_type(8)));
typedef float f32x4 __attribute__((ext_vector_type(4)));

__device__ __forceinline__ short f2bf(float f) {
    union { float f; unsigned u; } cv; cv.f = f;
    unsigned r = cv.u + 0x7FFFu + ((cv.u >> 16) & 1u);
    return (short)(r >> 16);
}
// pack two fp32 -> dword of two bf16 (round-half-up): lo16=bf(f0), hi16=bf(f1)
__device__ __forceinline__ unsigned pk2bf(float f0, float f1) {
    union { float f; unsigned u; } a, b; a.f = f0; b.f = f1;
    return __builtin_amdgcn_perm(b.u + 0x8000u, a.u + 0x8000u, 0x07060302u);
}

// ---------------- weight prep (fused Wf/b1') + time embedding ----------------
__global__ void prep_emb_kernel(const float* __restrict__ wpg, const float* __restrict__ bpg,
                                const float* __restrict__ w1g, const float* __restrict__ b1g,
                                const float* __restrict__ w2g, const float* __restrict__ b2g,
                                const float* __restrict__ w3g,
                                const int* __restrict__ t,
                                const float* __restrict__ wt, const float* __restrict__ bt,
                                short* __restrict__ wsb, float* __restrict__ wsf)
{
    const int bid = blockIdx.x, tid = threadIdx.x;
    if (bid < 64) {                       // Wf [128][128]: col = 32q + 10*c3 + k
        int i = bid * 256 + tid;
        int o = i >> 7, kk = i & 127;
        int qq = kk >> 5, r = kk & 31;
        float v = 0.f;
        if (r < 30 && (r % 10) < 9) {
            int c3 = r / 10, k = r % 10;
            int ic = 3 * qq + c3;
            #pragma unroll
            for (int j = 0; j < 4; ++j)
                v += w1g[o * 48 + 4 * ic + j] * wpg[(4 * ic + j) * 9 + k];
        }
        wsb[i] = f2bf(v);
        return;
    }
    if (bid < 128) {                      // w2 [128][128]
        int i = (bid - 64) * 256 + tid;
        wsb[16384 + i] = f2bf(w2g[i]);
        return;
    }
    if (bid == 128) {                     // w3 [12][128] -> [16][128] pad
        for (int j = tid; j < 2048; j += 256)
            wsb[32768 + j] = (j < 1536) ? f2bf(w3g[j]) : (short)0;
        return;
    }
    if (bid == 129) {                     // b1' = b1 + w1.bp ; b2 copy
        if (tid < 128) {
            float s = b1g[tid];
            #pragma unroll 4
            for (int c = 0; c < 48; ++c) s += w1g[tid * 48 + c] * bpg[c];
            wsf[WSF_B1 + tid] = s;
        } else {
            wsf[WSF_B2 + (tid - 128)] = b2g[tid - 128];
        }
        return;
    }
    int b = bid - 130;                    // time embedding, one block per batch
    int lane = threadIdx.x;
    if (lane >= 64) return;
    float tv = (float)t[b];
    float s0 = 0.f, s1 = 0.f, s2 = 0.f;
    const float LOG1E4 = 9.210340371976184f;
    #pragma unroll
    for (int ii = 0; ii < 2; ++ii) {
        int i = lane + ii * 64;
        float invf = __expf(-LOG1E4 * (float)i * (1.0f / 128.0f));
        float ang = tv * invf;
        float sn = sinf(ang), cs = cosf(ang);
        float ss = sn / (1.0f + __expf(-sn));
        float sc = cs / (1.0f + __expf(-cs));
        s0 += ss * wt[0 * 256 + i] + sc * wt[0 * 256 + i + 128];
        s1 += ss * wt[1 * 256 + i] + sc * wt[1 * 256 + i + 128];
        s2 += ss * wt[2 * 256 + i] + sc * wt[2 * 256 + i + 128];
    }
    #pragma unroll
    for (int off = 32; off; off >>= 1) {
        s0 += __shfl_down(s0, off);
        s1 += __shfl_down(s1, off);
        s2 += __shfl_down(s2, off);
    }
    if (lane == 0) {
        wsf[WSF_EMB + b * 3 + 0] = s0 + bt[0];
        wsf[WSF_EMB + b * 3 + 1] = s1 + bt[1];
        wsf[WSF_EMB + b * 3 + 2] = s2 + bt[2];
    }
}

// ---------------- main fused kernel ----------------
// MFMA 16x16x32 (m89): A lane(i=lane&15,q) holds A[i][q*8+j]; B symmetric:
// lane holds B[q*8+j][i]. D: col(N)=lane&15, row(M)=q*4+r.
// bufA timeline per iter: stage im2col (cols 0..127) -> B1 -> G1 reads it,
// writes h1S -> B2 -> G2 reads h1S, writes h2 -> bufA -> B3 -> G3 reads bufA
// -> B4 -> next iter's staging overwrites bufA.
__global__ __launch_bounds__(256, 3) void canet_main(
    const float* __restrict__ xg,   // (16,3,256,256)
    const float* __restrict__ hg,   // (16,9,256,256)
    const short* __restrict__ wsb,
    const float* __restrict__ wsf,
    float* __restrict__ outg)
{
    __shared__ __align__(16) short bufA[64 * ACT_S];   // im2col / h2
    __shared__ __align__(16) short h1S[64 * ACT_S];
    __shared__ __align__(16) short w3_s[12 * 128];     // [oc][k], col XOR-swizzled
    __shared__ __align__(16) float bias_s[256];        // b1' @0, b2 @128

    const int tid = threadIdx.x;
    const int b = blockIdx.x >> 8;
    const int y = blockIdx.x & 255;

    bias_s[tid] = wsf[WSF_B1 + tid];                   // b1'[0:128], b2[128:256]
    for (int i = tid; i < 1536; i += 256) {            // w3 [12][128] swizzled
        int row = i >> 7, col = i & 127;
        w3_s[(row << 7) + (col ^ ((row & 7) << 3))] = wsb[32768 + i];
    }

    const int wv = tid >> 6;
    const int lane = tid & 63;
    const int m = lane & 15;
    const int q = lane >> 4;

    // ---- persistent weight fragments (Wf, w2; 64 regs) ----
    bf16x8 w1f[2][4], w2f[2][4];
    #pragma unroll
    for (int j = 0; j < 2; ++j) {
        int n = wv * 32 + j * 16 + m;
        #pragma unroll
        for (int ks = 0; ks < 4; ++ks) {
            w1f[j][ks] = *(const bf16x8*)(wsb + n * 128 + ks * 32 + q * 8);
            w2f[j][ks] = *(const bf16x8*)(wsb + 16384 + n * 128 + ks * 32 + q * 8);
        }
    }
    const float embv = (m < 3) ? wsf[WSF_EMB + b * 3 + m] : 0.0f;

    // conv source pointers (lane's 3 input channels: ic = 3q + i3)
    const float* src3[3];
    #pragma unroll
    for (int i3 = 0; i3 < 3; ++i3) {
        int ic = 3 * q + i3;
        src3[i3] = (ic < 3) ? (xg + (((size_t)b * 3 + ic) << 16))
                            : (hg + (((size_t)b * 9 + (ic - 3)) << 16));
    }

    const int mm = (m < 12) ? m : 11;        // w3 row clamp (lanes 12-15 discarded)
    const int w3sw = (mm & 7) << 3;

    __syncthreads();   // staged LDS ready

    for (int it = 0; it < 4; ++it) {
        const int x0 = it * 64;
        const int px = x0 + wv * 16 + m;

        // ---- im2col staging: taps -> bf16 -> bufA[px][32q + 10*i3 + k] ----
        {
            const int xm1 = px - (px > 0);
            const int xp1 = px + (px < 255);
            const bool okl = (px > 0), okr = (px < 255);
            short* prow = bufA + (wv * 16 + m) * ACT_S + 32 * q;
            const bool interior = (y >= 1) && (y <= 254);
            #pragma unroll
            for (int i3 = 0; i3 < 3; ++i3) {
                const float* s = src3[i3];
                float tap[9];
                if (interior) {
                    #pragma unroll
                    for (int ky = 0; ky < 3; ++ky) {
                        const float* rp = s + (y + ky - 1) * 256;
                        float c0 = rp[xm1], c1 = rp[px], c2 = rp[xp1];
                        tap[ky * 3 + 0] = okl ? c0 : 0.0f;
                        tap[ky * 3 + 1] = c1;
                        tap[ky * 3 + 2] = okr ? c2 : 0.0f;
                    }
                } else {
                    #pragma unroll
                    for (int ky = 0; ky < 3; ++ky) {
                        int yy = y + ky - 1;
                        bool yok = (yy >= 0) && (yy < 256);
                        const float* rp = s + (yok ? yy : y) * 256;
                        float c0 = rp[xm1], c1 = rp[px], c2 = rp[xp1];
                        tap[ky * 3 + 0] = (yok && okl) ? c0 : 0.0f;
                        tap[ky * 3 + 1] = yok ? c1 : 0.0f;
                        tap[ky * 3 + 2] = (yok && okr) ? c2 : 0.0f;
                    }
                }
                unsigned* pw = (unsigned*)(prow + 10 * i3);   // 4B-aligned (even shorts)
                pw[0] = pk2bf(tap[0], tap[1]);
                pw[1] = pk2bf(tap[2], tap[3]);
                pw[2] = pk2bf(tap[4], tap[5]);
                pw[3] = pk2bf(tap[6], tap[7]);
                pw[4] = pk2bf(tap[8], 0.0f);                  // k=9 pad
            }
            *(unsigned*)(prow + 30) = 0u;                     // q-block pad 30,31
        }
        __syncthreads();   // B1: im2col ready

        // ---- GEMM1 (swapped): D[ch][px] = Wf . im2col^T ; write h1S[px][ch] ----
        #pragma unroll
        for (int nt = 0; nt < 4; ++nt) {
            f32x4 c0 = *(const f32x4*)(bias_s + wv * 32 + q * 4);
            f32x4 c1 = *(const f32x4*)(bias_s + wv * 32 + 16 + q * 4);
            #pragma unroll
            for (int ks = 0; ks < 4; ++ks) {
                bf16x8 p = *(const bf16x8*)(bufA + (nt * 16 + m) * ACT_S + ks * 32 + q * 8);
                c0 = __builtin_amdgcn_mfma_f32_16x16x32_bf16(w1f[0][ks], p, c0, 0, 0, 0);
                c1 = __builtin_amdgcn_mfma_f32_16x16x32_bf16(w1f[1][ks], p, c1, 0, 0, 0);
            }
            short* drow = h1S + (nt * 16 + m) * ACT_S + wv * 32 + q * 4;
            uint2 pk;
            pk.x = pk2bf(fmaxf(c0[0], 0.f), fmaxf(c0[1], 0.f));
            pk.y = pk2bf(fmaxf(c0[2], 0.f), fmaxf(c0[3], 0.f));
            *(uint2*)drow = pk;
            pk.x = pk2bf(fmaxf(c1[0], 0.f), fmaxf(c1[1], 0.f));
            pk.y = pk2bf(fmaxf(c1[2], 0.f), fmaxf(c1[3], 0.f));
            *(uint2*)(drow + 16) = pk;
        }
        __syncthreads();   // B2: h1 ready; im2col fully read

        // ---- GEMM2 (swapped): D[ch][px] = w2 . h1^T ; write h2 -> bufA ----
        #pragma unroll
        for (int nt = 0; nt < 4; ++nt) {
            f32x4 c0 = *(const f32x4*)(bias_s + 128 + wv * 32 + q * 4);
            f32x4 c1 = *(const f32x4*)(bias_s + 128 + wv * 32 + 16 + q * 4);
            #pragma unroll
            for (int ks = 0; ks < 4; ++ks) {
                bf16x8 a = *(const bf16x8*)(h1S + (nt * 16 + m) * ACT_S + ks * 32 + q * 8);
                c0 = __builtin_amdgcn_mfma_f32_16x16x32_bf16(w2f[0][ks], a, c0, 0, 0, 0);
                c1 = __builtin_amdgcn_mfma_f32_16x16x32_bf16(w2f[1][ks], a, c1, 0, 0, 0);
            }
            short* drow = bufA + (nt * 16 + m) * ACT_S + wv * 32 + q * 4;
            uint2 pk;
            pk.x = pk2bf(fmaxf(c0[0], 0.f), fmaxf(c0[1], 0.f));
            pk.y = pk2bf(fmaxf(c0[2], 0.f), fmaxf(c0[3], 0.f));
            *(uint2*)drow = pk;
            pk.x = pk2bf(fmaxf(c1[0], 0.f), fmaxf(c1[1], 0.f));
            pk.y = pk2bf(fmaxf(c1[2], 0.f), fmaxf(c1[3], 0.f));
            *(uint2*)(drow + 16) = pk;
        }
        __syncthreads();   // B3: h2 ready

        // ---- GEMM3: out = h2 . w3^T ; D col=oc, row=px; float4 store ----
        {
            f32x4 acc = {0.f, 0.f, 0.f, 0.f};
            #pragma unroll
            for (int ks = 0; ks < 4; ++ks) {
                bf16x8 a = *(const bf16x8*)(bufA + (wv * 16 + m) * ACT_S + ks * 32 + q * 8);
                bf16x8 w3k = *(const bf16x8*)(w3_s + (mm << 7) + ((ks * 32 + q * 8) ^ w3sw));
                acc = __builtin_amdgcn_mfma_f32_16x16x32_bf16(a, w3k, acc, 0, 0, 0);
            }
            if (m < 12) {
                int xx0 = x0 + wv * 16 + q * 4;
                size_t idx;
                if (m < 3) {
                    idx = (size_t)NOISE_BASE + (((size_t)b * 3 + m) << 16) + (size_t)y * 256 + xx0;
                } else {
                    idx = (((size_t)b * 9 + (m - 3)) << 16) + (size_t)y * 256 + xx0;
                }
                f32x4 vst = {acc[0] + embv, acc[1] + embv, acc[2] + embv, acc[3] + embv};
                *(f32x4*)(outg + idx) = vst;
            }
        }
        __syncthreads();   // B4: bufA fully read; next staging may overwrite
    }
}

extern "C" void kernel_launch(void* const* d_in, const int* in_sizes, int n_in,
                              void* d_out, int out_size, void* d_ws, size_t ws_size,
                              hipStream_t stream) {
    const float* xg  = (const float*)d_in[0];
    const float* hg  = (const float*)d_in[1];
    const int*   tg  = (const int*)  d_in[2];
    const float* wpg = (const float*)d_in[3];
    const float* bpg = (const float*)d_in[4];
    const float* w1g = (const float*)d_in[5];
    const float* b1g = (const float*)d_in[6];
    const float* w2g = (const float*)d_in[7];
    const float* b2g = (const float*)d_in[8];
    const float* w3g = (const float*)d_in[9];
    const float* wtg = (const float*)d_in[10];
    const float* btg = (const float*)d_in[11];
    float* outg = (float*)d_out;
    short* wsb  = (short*)d_ws;
    float* wsf  = (float*)d_ws + WSF_OFF;

    prep_emb_kernel<<<146, 256, 0, stream>>>(wpg, bpg, w1g, b1g, w2g, b2g, w3g,
                                             tg, wtg, btg, wsb, wsf);
    canet_main<<<4096, 256, 0, stream>>>(xg, hg, wsb, wsf, outg);
}

// Round 11
// 217.245 us; speedup vs baseline: 1.1357x; 1.0084x over previous
//
#include <hip/hip_runtime.h>

// CANet fused kernel, round 16 == round 14 third submission (2x container
// infra failure on this source; crash-mechanism audit: permch changes only
// DATA, all addressing deltas verified aligned+in-bounds, barriers uniform --
// no mechanism for a kernel-caused container kill. r1->r7 precedent: identical
// failure mode resubmitted clean. Three-strike policy: next failure reverts
// to r13 and splits this experiment in two.)
// Post-mortem r13: conv-fold WIN (139->131.7us, VALUBusy 40->36). Conflicts
// 12.6->18.9M; the +2.1M from r11's w3_s reads (~8 cyc/read despite broadcast
// clamp) calibrates the conflict domain as >=16 lanes. Under that model the
// dominant conflicters are the b64 activation WRITES (rows m, m+8 collide:
// 4m mod 32) and staging b32s -- not the b128 reads (4/slot = cycle-minimum).
// This round: make all hot LDS writes b128 in the optimal (m+q)&7 slot family:
//  - Channel permutation o(f)=base+8*(i>>2)+4j+(i&3) applied to Wf/w2 fragment
//    rows in prep: lane's c0+c1 D-values become 8 CONTIGUOUS chs -> ONE uint4
//    write per nt (was 2 conflicting uint2). h1S/bufA positions stay identity-
//    ch-indexed; readers unchanged. Bias reads move to +8q/+8q+4.
//  - Staging: 16 u32 -> rr[16] regs -> 4 uint4 writes.
//  - w3_s: full 16 zero-padded rows (no clamp), uniform 2-way max.
// Canaries: WRITE 49152KB / FETCH ~74MB flat (spill); conflicts <10M or the
// conflict model is wrong again.

#define ACT_S 136     // 272 B rows (16B-aligned) for bufA/h1S [px][ch]
#define NOISE_BASE 9437184   // 16*9*65536

// d_ws shorts: Wf[128][128]@0, w2[128][128]@16384, w3[16][128]@32768 (2048)
// floats @ WSF_OFF: b1'[128]@0, b2[128]@128, emb[48]@256
#define WSF_OFF 17408
#define WSF_B1 0
#define WSF_B2 128
#define WSF_EMB 256

typedef short bf16x8 __attribute__((ext_vector_type(8)));
typedef float f32x4 __attribute__((ext_vector_type(4)));

__device__ __forceinline__ short f2bf(float f) {
    union { float f; unsigned u; } cv; cv.f = f;
    unsigned r = cv.u + 0x7FFFu + ((cv.u >> 16) & 1u);
    return (short)(r >> 16);
}
// pack two fp32 -> dword of two bf16 (round-half-up): lo16=bf(f0), hi16=bf(f1)
__device__ __forceinline__ unsigned pk2bf(float f0, float f1) {
    union { float f; unsigned u; } a, b; a.f = f0; b.f = f1;
    return __builtin_amdgcn_perm(b.u + 0x8000u, a.u + 0x8000u, 0x07060302u);
}

// fragment-row -> actual channel permutation (within each 32-ch wave block):
// f = base(32) + 16*j + i  ->  o = base + 8*(i>>2) + 4*j + (i&3)
__device__ __forceinline__ int permch(int f) {
    return (f & ~31) + 8 * ((f & 15) >> 2) + 4 * ((f >> 4) & 1) + (f & 3);
}

// ---------------- weight prep (fused Wf/b1') + time embedding ----------------
__global__ void prep_emb_kernel(const float* __restrict__ wpg, const float* __restrict__ bpg,
                                const float* __restrict__ w1g, const float* __restrict__ b1g,
                                const float* __restrict__ w2g, const float* __restrict__ b2g,
                                const float* __restrict__ w3g,
                                const int* __restrict__ t,
                                const float* __restrict__ wt, const float* __restrict__ bt,
                                short* __restrict__ wsb, float* __restrict__ wsf)
{
    const int bid = blockIdx.x, tid = threadIdx.x;
    if (bid < 64) {                       // Wf fragment rows (PERMUTED out-ch)
        int i = bid * 256 + tid;
        int f = i >> 7, kk = i & 127;
        int o = permch(f);
        int qq = kk >> 5, r = kk & 31;
        float v = 0.f;
        if (r < 30 && (r % 10) < 9) {
            int c3 = r / 10, k = r % 10;
            int ic = 3 * qq + c3;
            #pragma unroll
            for (int j = 0; j < 4; ++j)
                v += w1g[o * 48 + 4 * ic + j] * wpg[(4 * ic + j) * 9 + k];
        }
        wsb[i] = f2bf(v);
        return;
    }
    if (bid < 128) {                      // w2 fragment rows (PERMUTED out-ch)
        int i = (bid - 64) * 256 + tid;
        int f = i >> 7, col = i & 127;
        wsb[16384 + i] = f2bf(w2g[permch(f) * 128 + col]);
        return;
    }
    if (bid == 128) {                     // w3 [12][128] -> [16][128] pad
        for (int j = tid; j < 2048; j += 256)
            wsb[32768 + j] = (j < 1536) ? f2bf(w3g[j]) : (short)0;
        return;
    }
    if (bid == 129) {                     // b1' = b1 + w1.bp ; b2 copy (identity)
        if (tid < 128) {
            float s = b1g[tid];
            #pragma unroll 4
            for (int c = 0; c < 48; ++c) s += w1g[tid * 48 + c] * bpg[c];
            wsf[WSF_B1 + tid] = s;
        } else {
            wsf[WSF_B2 + (tid - 128)] = b2g[tid - 128];
        }
        return;
    }
    int b = bid - 130;                    // time embedding, one block per batch
    int lane = threadIdx.x;
    if (lane >= 64) return;
    float tv = (float)t[b];
    float s0 = 0.f, s1 = 0.f, s2 = 0.f;
    const float LOG1E4 = 9.210340371976184f;
    #pragma unroll
    for (int ii = 0; ii < 2; ++ii) {
        int i = lane + ii * 64;
        float invf = __expf(-LOG1E4 * (float)i * (1.0f / 128.0f));
        float ang = tv * invf;
        float sn = sinf(ang), cs = cosf(ang);
        float ss = sn / (1.0f + __expf(-sn));
        float sc = cs / (1.0f + __expf(-cs));
        s0 += ss * wt[0 * 256 + i] + sc * wt[0 * 256 + i + 128];
        s1 += ss * wt[1 * 256 + i] + sc * wt[1 * 256 + i + 128];
        s2 += ss * wt[2 * 256 + i] + sc * wt[2 * 256 + i + 128];
    }
    #pragma unroll
    for (int off = 32; off; off >>= 1) {
        s0 += __shfl_down(s0, off);
        s1 += __shfl_down(s1, off);
        s2 += __shfl_down(s2, off);
    }
    if (lane == 0) {
        wsf[WSF_EMB + b * 3 + 0] = s0 + bt[0];
        wsf[WSF_EMB + b * 3 + 1] = s1 + bt[1];
        wsf[WSF_EMB + b * 3 + 2] = s2 + bt[2];
    }
}

// ---------------- main fused kernel ----------------
// MFMA 16x16x32 (m89): A lane(i=lane&15,q) holds A[i][q*8+j]; B symmetric:
// lane holds B[q*8+j][i]. D: col(N)=lane&15, row(M)=q*4+r.
// With permch'd A-fragments, lane (m,q)'s c0(j=0)+c1(j=1) = chs base+8q+0..7
// (contiguous) for px=m -> one uint4 LDS write; positions stay ch-indexed.
__global__ __launch_bounds__(256, 3) void canet_main(
    const float* __restrict__ xg,   // (16,3,256,256)
    const float* __restrict__ hg,   // (16,9,256,256)
    const short* __restrict__ wsb,
    const float* __restrict__ wsf,
    float* __restrict__ outg)
{
    __shared__ __align__(16) short bufA[64 * ACT_S];   // im2col / h2
    __shared__ __align__(16) short h1S[64 * ACT_S];
    __shared__ __align__(16) short w3_s[16 * 128];     // [oc pad16][k], col XOR-swizzled
    __shared__ __align__(16) float bias_s[256];        // b1' @0, b2 @128

    const int tid = threadIdx.x;
    const int b = blockIdx.x >> 8;
    const int y = blockIdx.x & 255;

    bias_s[tid] = wsf[WSF_B1 + tid];                   // b1'[0:128], b2[128:256]
    for (int i = tid; i < 2048; i += 256) {            // w3 [16][128] swizzled
        int row = i >> 7, col = i & 127;
        w3_s[(row << 7) + (col ^ ((row & 7) << 3))] = wsb[32768 + i];
    }

    const int wv = tid >> 6;
    const int lane = tid & 63;
    const int m = lane & 15;
    const int q = lane >> 4;

    // ---- persistent weight fragments (Wf, w2; 64 regs; rows pre-permuted) ----
    bf16x8 w1f[2][4], w2f[2][4];
    #pragma unroll
    for (int j = 0; j < 2; ++j) {
        int n = wv * 32 + j * 16 + m;
        #pragma unroll
        for (int ks = 0; ks < 4; ++ks) {
            w1f[j][ks] = *(const bf16x8*)(wsb + n * 128 + ks * 32 + q * 8);
            w2f[j][ks] = *(const bf16x8*)(wsb + 16384 + n * 128 + ks * 32 + q * 8);
        }
    }
    const float embv = (m < 3) ? wsf[WSF_EMB + b * 3 + m] : 0.0f;

    // conv source pointers (lane's 3 input channels: ic = 3q + i3)
    const float* src3[3];
    #pragma unroll
    for (int i3 = 0; i3 < 3; ++i3) {
        int ic = 3 * q + i3;
        src3[i3] = (ic < 3) ? (xg + (((size_t)b * 3 + ic) << 16))
                            : (hg + (((size_t)b * 9 + (ic - 3)) << 16));
    }

    const int w3sw = (m & 7) << 3;

    __syncthreads();   // staged LDS ready

    for (int it = 0; it < 4; ++it) {
        const int x0 = it * 64;
        const int px = x0 + wv * 16 + m;

        // ---- im2col staging: taps -> bf16 -> 4 x uint4 -> bufA[px][32q+...] ----
        {
            const int xm1 = px - (px > 0);
            const int xp1 = px + (px < 255);
            const bool okl = (px > 0), okr = (px < 255);
            short* prow = bufA + (wv * 16 + m) * ACT_S + 32 * q;
            const bool interior = (y >= 1) && (y <= 254);
            unsigned rr[16];
            rr[15] = 0u;                                  // shorts 30,31 pad
            #pragma unroll
            for (int i3 = 0; i3 < 3; ++i3) {
                const float* s = src3[i3];
                float tap[9];
                if (interior) {
                    #pragma unroll
                    for (int ky = 0; ky < 3; ++ky) {
                        const float* rp = s + (y + ky - 1) * 256;
                        float c0 = rp[xm1], c1 = rp[px], c2 = rp[xp1];
                        tap[ky * 3 + 0] = okl ? c0 : 0.0f;
                        tap[ky * 3 + 1] = c1;
                        tap[ky * 3 + 2] = okr ? c2 : 0.0f;
                    }
                } else {
                    #pragma unroll
                    for (int ky = 0; ky < 3; ++ky) {
                        int yy = y + ky - 1;
                        bool yok = (yy >= 0) && (yy < 256);
                        const float* rp = s + (yok ? yy : y) * 256;
                        float c0 = rp[xm1], c1 = rp[px], c2 = rp[xp1];
                        tap[ky * 3 + 0] = (yok && okl) ? c0 : 0.0f;
                        tap[ky * 3 + 1] = yok ? c1 : 0.0f;
                        tap[ky * 3 + 2] = (yok && okr) ? c2 : 0.0f;
                    }
                }
                rr[5 * i3 + 0] = pk2bf(tap[0], tap[1]);
                rr[5 * i3 + 1] = pk2bf(tap[2], tap[3]);
                rr[5 * i3 + 2] = pk2bf(tap[4], tap[5]);
                rr[5 * i3 + 3] = pk2bf(tap[6], tap[7]);
                rr[5 * i3 + 4] = pk2bf(tap[8], 0.0f);     // k=9 pad
            }
            #pragma unroll
            for (int w = 0; w < 4; ++w) {
                uint4 v; v.x = rr[4*w]; v.y = rr[4*w+1]; v.z = rr[4*w+2]; v.w = rr[4*w+3];
                *(uint4*)(prow + 8 * w) = v;
            }
        }
        __syncthreads();   // B1: im2col ready

        // ---- GEMM1 (swapped, permuted): write h1S[px][ch] as one uint4 ----
        #pragma unroll
        for (int nt = 0; nt < 4; ++nt) {
            f32x4 c0 = *(const f32x4*)(bias_s + wv * 32 + 8 * q);
            f32x4 c1 = *(const f32x4*)(bias_s + wv * 32 + 8 * q + 4);
            #pragma unroll
            for (int ks = 0; ks < 4; ++ks) {
                bf16x8 p = *(const bf16x8*)(bufA + (nt * 16 + m) * ACT_S + ks * 32 + q * 8);
                c0 = __builtin_amdgcn_mfma_f32_16x16x32_bf16(w1f[0][ks], p, c0, 0, 0, 0);
                c1 = __builtin_amdgcn_mfma_f32_16x16x32_bf16(w1f[1][ks], p, c1, 0, 0, 0);
            }
            short* drow = h1S + (nt * 16 + m) * ACT_S + wv * 32 + 8 * q;
            uint4 pk4;
            pk4.x = pk2bf(fmaxf(c0[0], 0.f), fmaxf(c0[1], 0.f));
            pk4.y = pk2bf(fmaxf(c0[2], 0.f), fmaxf(c0[3], 0.f));
            pk4.z = pk2bf(fmaxf(c1[0], 0.f), fmaxf(c1[1], 0.f));
            pk4.w = pk2bf(fmaxf(c1[2], 0.f), fmaxf(c1[3], 0.f));
            *(uint4*)drow = pk4;
        }
        __syncthreads();   // B2: h1 ready; im2col fully read

        // ---- GEMM2 (swapped, permuted): write h2 -> bufA as one uint4 ----
        #pragma unroll
        for (int nt = 0; nt < 4; ++nt) {
            f32x4 c0 = *(const f32x4*)(bias_s + 128 + wv * 32 + 8 * q);
            f32x4 c1 = *(const f32x4*)(bias_s + 128 + wv * 32 + 8 * q + 4);
            #pragma unroll
            for (int ks = 0; ks < 4; ++ks) {
                bf16x8 a = *(const bf16x8*)(h1S + (nt * 16 + m) * ACT_S + ks * 32 + q * 8);
                c0 = __builtin_amdgcn_mfma_f32_16x16x32_bf16(w2f[0][ks], a, c0, 0, 0, 0);
                c1 = __builtin_amdgcn_mfma_f32_16x16x32_bf16(w2f[1][ks], a, c1, 0, 0, 0);
            }
            short* drow = bufA + (nt * 16 + m) * ACT_S + wv * 32 + 8 * q;
            uint4 pk4;
            pk4.x = pk2bf(fmaxf(c0[0], 0.f), fmaxf(c0[1], 0.f));
            pk4.y = pk2bf(fmaxf(c0[2], 0.f), fmaxf(c0[3], 0.f));
            pk4.z = pk2bf(fmaxf(c1[0], 0.f), fmaxf(c1[1], 0.f));
            pk4.w = pk2bf(fmaxf(c1[2], 0.f), fmaxf(c1[3], 0.f));
            *(uint4*)drow = pk4;
        }
        __syncthreads();   // B3: h2 ready

        // ---- GEMM3: out = h2 . w3^T ; D col=oc, row=px; float4 store ----
        {
            f32x4 acc = {0.f, 0.f, 0.f, 0.f};
            #pragma unroll
            for (int ks = 0; ks < 4; ++ks) {
                bf16x8 a = *(const bf16x8*)(bufA + (wv * 16 + m) * ACT_S + ks * 32 + q * 8);
                bf16x8 w3k = *(const bf16x8*)(w3_s + (m << 7) + ((ks * 32 + q * 8) ^ w3sw));
                acc = __builtin_amdgcn_mfma_f32_16x16x32_bf16(a, w3k, acc, 0, 0, 0);
            }
            if (m < 12) {
                int xx0 = x0 + wv * 16 + q * 4;
                size_t idx;
                if (m < 3) {
                    idx = (size_t)NOISE_BASE + (((size_t)b * 3 + m) << 16) + (size_t)y * 256 + xx0;
                } else {
                    idx = (((size_t)b * 9 + (m - 3)) << 16) + (size_t)y * 256 + xx0;
                }
                f32x4 vst = {acc[0] + embv, acc[1] + embv, acc[2] + embv, acc[3] + embv};
                *(f32x4*)(outg + idx) = vst;
            }
        }
        __syncthreads();   // B4: bufA fully read; next staging may overwrite
    }
}

extern "C" void kernel_launch(void* const* d_in, const int* in_sizes, int n_in,
                              void* d_out, int out_size, void* d_ws, size_t ws_size,
                              hipStream_t stream) {
    const float* xg  = (const float*)d_in[0];
    const float* hg  = (const float*)d_in[1];
    const int*   tg  = (const int*)  d_in[2];
    const float* wpg = (const float*)d_in[3];
    const float* bpg = (const float*)d_in[4];
    const float* w1g = (const float*)d_in[5];
    const float* b1g = (const float*)d_in[6];
    const float* w2g = (const float*)d_in[7];
    const float* b2g = (const float*)d_in[8];
    const float* w3g = (const float*)d_in[9];
    const float* wtg = (const float*)d_in[10];
    const float* btg = (const float*)d_in[11];
    float* outg = (float*)d_out;
    short* wsb  = (short*)d_ws;
    float* wsf  = (float*)d_ws + WSF_OFF;

    prep_emb_kernel<<<146, 256, 0, stream>>>(wpg, bpg, w1g, b1g, w2g, b2g, w3g,
                                             tg, wtg, btg, wsb, wsf);
    canet_main<<<4096, 256, 0, stream>>>(xg, hg, wsb, wsf, outg);
}

// Round 12
// 204.884 us; speedup vs baseline: 1.2042x; 1.0603x over previous
//
#include <hip/hip_runtime.h>

// CANet fused kernel, round 17.
// Post-mortem r14: conflict model CONFIRMED (18.9M->10.5M, predicted <10M) but
// only -3us (131.7->128.3): remaining conflicts are overlap-hidden; conflict
// chase closed. Stall analysis: 271K cyc/CU vs ~45K issue-work -> phases are
// latency-dominated; dominant chain = conv staging's 27 global loads (partly
// HBM-cold ~900cyc; FETCH 74MB > 50MB input) feeding mask->pack->write->B1.
// r17 = r14 + ONE change: tap PREFETCH (r9's mechanism, which failed only from
// the (256,4) reg cap). Now: bound(256,3) budget ~170, VGPR 84 -> +40 peak
// fits. Issue it+1's 27 raw clamped loads right after B1; they land under
// G1/G2/G3 (>=2.6K cyc cover vs ~900 needed). Masks applied at consume.
// Canaries: WRITE 49152KB / FETCH ~74MB flat (spill = revert); VGPR <= ~140.
// If dur flat: staging latency not critical path -> attack barrier structure.

#define ACT_S 136     // 272 B rows (16B-aligned) for bufA/h1S [px][ch]
#define NOISE_BASE 9437184   // 16*9*65536

// d_ws shorts: Wf[128][128]@0, w2[128][128]@16384, w3[16][128]@32768 (2048)
// floats @ WSF_OFF: b1'[128]@0, b2[128]@128, emb[48]@256
#define WSF_OFF 17408
#define WSF_B1 0
#define WSF_B2 128
#define WSF_EMB 256

typedef short bf16x8 __attribute__((ext_vector_type(8)));
typedef float f32x4 __attribute__((ext_vector_type(4)));

__device__ __forceinline__ short f2bf(float f) {
    union { float f; unsigned u; } cv; cv.f = f;
    unsigned r = cv.u + 0x7FFFu + ((cv.u >> 16) & 1u);
    return (short)(r >> 16);
}
// pack two fp32 -> dword of two bf16 (round-half-up): lo16=bf(f0), hi16=bf(f1)
__device__ __forceinline__ unsigned pk2bf(float f0, float f1) {
    union { float f; unsigned u; } a, b; a.f = f0; b.f = f1;
    return __builtin_amdgcn_perm(b.u + 0x8000u, a.u + 0x8000u, 0x07060302u);
}

// fragment-row -> actual channel permutation (within each 32-ch wave block):
// f = base(32) + 16*j + i  ->  o = base + 8*(i>>2) + 4*j + (i&3)
__device__ __forceinline__ int permch(int f) {
    return (f & ~31) + 8 * ((f & 15) >> 2) + 4 * ((f >> 4) & 1) + (f & 3);
}

// ---------------- weight prep (fused Wf/b1') + time embedding ----------------
__global__ void prep_emb_kernel(const float* __restrict__ wpg, const float* __restrict__ bpg,
                                const float* __restrict__ w1g, const float* __restrict__ b1g,
                                const float* __restrict__ w2g, const float* __restrict__ b2g,
                                const float* __restrict__ w3g,
                                const int* __restrict__ t,
                                const float* __restrict__ wt, const float* __restrict__ bt,
                                short* __restrict__ wsb, float* __restrict__ wsf)
{
    const int bid = blockIdx.x, tid = threadIdx.x;
    if (bid < 64) {                       // Wf fragment rows (PERMUTED out-ch)
        int i = bid * 256 + tid;
        int f = i >> 7, kk = i & 127;
        int o = permch(f);
        int qq = kk >> 5, r = kk & 31;
        float v = 0.f;
        if (r < 30 && (r % 10) < 9) {
            int c3 = r / 10, k = r % 10;
            int ic = 3 * qq + c3;
            #pragma unroll
            for (int j = 0; j < 4; ++j)
                v += w1g[o * 48 + 4 * ic + j] * wpg[(4 * ic + j) * 9 + k];
        }
        wsb[i] = f2bf(v);
        return;
    }
    if (bid < 128) {                      // w2 fragment rows (PERMUTED out-ch)
        int i = (bid - 64) * 256 + tid;
        int f = i >> 7, col = i & 127;
        wsb[16384 + i] = f2bf(w2g[permch(f) * 128 + col]);
        return;
    }
    if (bid == 128) {                     // w3 [12][128] -> [16][128] pad
        for (int j = tid; j < 2048; j += 256)
            wsb[32768 + j] = (j < 1536) ? f2bf(w3g[j]) : (short)0;
        return;
    }
    if (bid == 129) {                     // b1' = b1 + w1.bp ; b2 copy (identity)
        if (tid < 128) {
            float s = b1g[tid];
            #pragma unroll 4
            for (int c = 0; c < 48; ++c) s += w1g[tid * 48 + c] * bpg[c];
            wsf[WSF_B1 + tid] = s;
        } else {
            wsf[WSF_B2 + (tid - 128)] = b2g[tid - 128];
        }
        return;
    }
    int b = bid - 130;                    // time embedding, one block per batch
    int lane = threadIdx.x;
    if (lane >= 64) return;
    float tv = (float)t[b];
    float s0 = 0.f, s1 = 0.f, s2 = 0.f;
    const float LOG1E4 = 9.210340371976184f;
    #pragma unroll
    for (int ii = 0; ii < 2; ++ii) {
        int i = lane + ii * 64;
        float invf = __expf(-LOG1E4 * (float)i * (1.0f / 128.0f));
        float ang = tv * invf;
        float sn = sinf(ang), cs = cosf(ang);
        float ss = sn / (1.0f + __expf(-sn));
        float sc = cs / (1.0f + __expf(-cs));
        s0 += ss * wt[0 * 256 + i] + sc * wt[0 * 256 + i + 128];
        s1 += ss * wt[1 * 256 + i] + sc * wt[1 * 256 + i + 128];
        s2 += ss * wt[2 * 256 + i] + sc * wt[2 * 256 + i + 128];
    }
    #pragma unroll
    for (int off = 32; off; off >>= 1) {
        s0 += __shfl_down(s0, off);
        s1 += __shfl_down(s1, off);
        s2 += __shfl_down(s2, off);
    }
    if (lane == 0) {
        wsf[WSF_EMB + b * 3 + 0] = s0 + bt[0];
        wsf[WSF_EMB + b * 3 + 1] = s1 + bt[1];
        wsf[WSF_EMB + b * 3 + 2] = s2 + bt[2];
    }
}

// ---------------- main fused kernel ----------------
// MFMA 16x16x32 (m89): A lane(i=lane&15,q) holds A[i][q*8+j]; B symmetric:
// lane holds B[q*8+j][i]. D: col(N)=lane&15, row(M)=q*4+r.
// With permch'd A-fragments, lane (m,q)'s c0(j=0)+c1(j=1) = chs base+8q+0..7
// (contiguous) for px=m -> one uint4 LDS write; positions stay ch-indexed.
__global__ __launch_bounds__(256, 3) void canet_main(
    const float* __restrict__ xg,   // (16,3,256,256)
    const float* __restrict__ hg,   // (16,9,256,256)
    const short* __restrict__ wsb,
    const float* __restrict__ wsf,
    float* __restrict__ outg)
{
    __shared__ __align__(16) short bufA[64 * ACT_S];   // im2col / h2
    __shared__ __align__(16) short h1S[64 * ACT_S];
    __shared__ __align__(16) short w3_s[16 * 128];     // [oc pad16][k], col XOR-swizzled
    __shared__ __align__(16) float bias_s[256];        // b1' @0, b2 @128

    const int tid = threadIdx.x;
    const int b = blockIdx.x >> 8;
    const int y = blockIdx.x & 255;

    bias_s[tid] = wsf[WSF_B1 + tid];                   // b1'[0:128], b2[128:256]
    for (int i = tid; i < 2048; i += 256) {            // w3 [16][128] swizzled
        int row = i >> 7, col = i & 127;
        w3_s[(row << 7) + (col ^ ((row & 7) << 3))] = wsb[32768 + i];
    }

    const int wv = tid >> 6;
    const int lane = tid & 63;
    const int m = lane & 15;
    const int q = lane >> 4;

    // ---- persistent weight fragments (Wf, w2; 64 regs; rows pre-permuted) ----
    bf16x8 w1f[2][4], w2f[2][4];
    #pragma unroll
    for (int j = 0; j < 2; ++j) {
        int n = wv * 32 + j * 16 + m;
        #pragma unroll
        for (int ks = 0; ks < 4; ++ks) {
            w1f[j][ks] = *(const bf16x8*)(wsb + n * 128 + ks * 32 + q * 8);
            w2f[j][ks] = *(const bf16x8*)(wsb + 16384 + n * 128 + ks * 32 + q * 8);
        }
    }
    const float embv = (m < 3) ? wsf[WSF_EMB + b * 3 + m] : 0.0f;

    // conv source pointers (lane's 3 input channels: ic = 3q + i3)
    const float* src3[3];
    #pragma unroll
    for (int i3 = 0; i3 < 3; ++i3) {
        int ic = 3 * q + i3;
        src3[i3] = (ic < 3) ? (xg + (((size_t)b * 3 + ic) << 16))
                            : (hg + (((size_t)b * 9 + (ic - 3)) << 16));
    }
    // clamped y-row offsets + validity (uniform per block)
    int yoff[3]; bool yokk[3];
    #pragma unroll
    for (int ky = 0; ky < 3; ++ky) {
        int yy = y + ky - 1;
        yokk[ky] = (yy >= 0) && (yy < 256);
        yoff[ky] = (yokk[ky] ? yy : y) * 256;
    }

    // raw (unmasked, addr-clamped) tap loads for pixel pxl into tp[27]
    auto load_taps = [&](float (&tp)[27], int pxl) {
        const int xm1 = pxl - (pxl > 0);
        const int xp1 = pxl + (pxl < 255);
        #pragma unroll
        for (int i3 = 0; i3 < 3; ++i3) {
            #pragma unroll
            for (int ky = 0; ky < 3; ++ky) {
                const float* rp = src3[i3] + yoff[ky];
                tp[i3 * 9 + ky * 3 + 0] = rp[xm1];
                tp[i3 * 9 + ky * 3 + 1] = rp[pxl];
                tp[i3 * 9 + ky * 3 + 2] = rp[xp1];
            }
        }
    };

    const int w3sw = (m & 7) << 3;

    float tp[27];
    load_taps(tp, wv * 16 + m);     // it=0 prefetch (global only, pre-barrier ok)

    __syncthreads();   // staged LDS ready

    for (int it = 0; it < 4; ++it) {
        const int x0 = it * 64;
        const int px = x0 + wv * 16 + m;

        // ---- im2col staging: mask prefetched taps -> bf16 -> 4 x uint4 ----
        {
            const bool okl = (px > 0), okr = (px < 255);
            short* prow = bufA + (wv * 16 + m) * ACT_S + 32 * q;
            unsigned rr[16];
            rr[15] = 0u;                                  // shorts 30,31 pad
            #pragma unroll
            for (int i3 = 0; i3 < 3; ++i3) {
                float tm[9];
                #pragma unroll
                for (int ky = 0; ky < 3; ++ky) {
                    int o = i3 * 9 + ky * 3;
                    tm[ky * 3 + 0] = (yokk[ky] && okl) ? tp[o + 0] : 0.0f;
                    tm[ky * 3 + 1] = yokk[ky] ? tp[o + 1] : 0.0f;
                    tm[ky * 3 + 2] = (yokk[ky] && okr) ? tp[o + 2] : 0.0f;
                }
                rr[5 * i3 + 0] = pk2bf(tm[0], tm[1]);
                rr[5 * i3 + 1] = pk2bf(tm[2], tm[3]);
                rr[5 * i3 + 2] = pk2bf(tm[4], tm[5]);
                rr[5 * i3 + 3] = pk2bf(tm[6], tm[7]);
                rr[5 * i3 + 4] = pk2bf(tm[8], 0.0f);      // k=9 pad
            }
            #pragma unroll
            for (int w = 0; w < 4; ++w) {
                uint4 v; v.x = rr[4*w]; v.y = rr[4*w+1]; v.z = rr[4*w+2]; v.w = rr[4*w+3];
                *(uint4*)(prow + 8 * w) = v;
            }
        }
        __syncthreads();   // B1: im2col ready

        // prefetch it+1's taps now; latency hides under G1/G2/G3 (>=2.6K cyc)
        if (it < 3) load_taps(tp, px + 64);

        // ---- GEMM1 (swapped, permuted): write h1S[px][ch] as one uint4 ----
        #pragma unroll
        for (int nt = 0; nt < 4; ++nt) {
            f32x4 c0 = *(const f32x4*)(bias_s + wv * 32 + 8 * q);
            f32x4 c1 = *(const f32x4*)(bias_s + wv * 32 + 8 * q + 4);
            #pragma unroll
            for (int ks = 0; ks < 4; ++ks) {
                bf16x8 p = *(const bf16x8*)(bufA + (nt * 16 + m) * ACT_S + ks * 32 + q * 8);
                c0 = __builtin_amdgcn_mfma_f32_16x16x32_bf16(w1f[0][ks], p, c0, 0, 0, 0);
                c1 = __builtin_amdgcn_mfma_f32_16x16x32_bf16(w1f[1][ks], p, c1, 0, 0, 0);
            }
            short* drow = h1S + (nt * 16 + m) * ACT_S + wv * 32 + 8 * q;
            uint4 pk4;
            pk4.x = pk2bf(fmaxf(c0[0], 0.f), fmaxf(c0[1], 0.f));
            pk4.y = pk2bf(fmaxf(c0[2], 0.f), fmaxf(c0[3], 0.f));
            pk4.z = pk2bf(fmaxf(c1[0], 0.f), fmaxf(c1[1], 0.f));
            pk4.w = pk2bf(fmaxf(c1[2], 0.f), fmaxf(c1[3], 0.f));
            *(uint4*)drow = pk4;
        }
        __syncthreads();   // B2: h1 ready; im2col fully read

        // ---- GEMM2 (swapped, permuted): write h2 -> bufA as one uint4 ----
        #pragma unroll
        for (int nt = 0; nt < 4; ++nt) {
            f32x4 c0 = *(const f32x4*)(bias_s + 128 + wv * 32 + 8 * q);
            f32x4 c1 = *(const f32x4*)(bias_s + 128 + wv * 32 + 8 * q + 4);
            #pragma unroll
            for (int ks = 0; ks < 4; ++ks) {
                bf16x8 a = *(const bf16x8*)(h1S + (nt * 16 + m) * ACT_S + ks * 32 + q * 8);
                c0 = __builtin_amdgcn_mfma_f32_16x16x32_bf16(w2f[0][ks], a, c0, 0, 0, 0);
                c1 = __builtin_amdgcn_mfma_f32_16x16x32_bf16(w2f[1][ks], a, c1, 0, 0, 0);
            }
            short* drow = bufA + (nt * 16 + m) * ACT_S + wv * 32 + 8 * q;
            uint4 pk4;
            pk4.x = pk2bf(fmaxf(c0[0], 0.f), fmaxf(c0[1], 0.f));
            pk4.y = pk2bf(fmaxf(c0[2], 0.f), fmaxf(c0[3], 0.f));
            pk4.z = pk2bf(fmaxf(c1[0], 0.f), fmaxf(c1[1], 0.f));
            pk4.w = pk2bf(fmaxf(c1[2], 0.f), fmaxf(c1[3], 0.f));
            *(uint4*)drow = pk4;
        }
        __syncthreads();   // B3: h2 ready

        // ---- GEMM3: out = h2 . w3^T ; D col=oc, row=px; float4 store ----
        {
            f32x4 acc = {0.f, 0.f, 0.f, 0.f};
            #pragma unroll
            for (int ks = 0; ks < 4; ++ks) {
                bf16x8 a = *(const bf16x8*)(bufA + (wv * 16 + m) * ACT_S + ks * 32 + q * 8);
                bf16x8 w3k = *(const bf16x8*)(w3_s + (m << 7) + ((ks * 32 + q * 8) ^ w3sw));
                acc = __builtin_amdgcn_mfma_f32_16x16x32_bf16(a, w3k, acc, 0, 0, 0);
            }
            if (m < 12) {
                int xx0 = x0 + wv * 16 + q * 4;
                size_t idx;
                if (m < 3) {
                    idx = (size_t)NOISE_BASE + (((size_t)b * 3 + m) << 16) + (size_t)y * 256 + xx0;
                } else {
                    idx = (((size_t)b * 9 + (m - 3)) << 16) + (size_t)y * 256 + xx0;
                }
                f32x4 vst = {acc[0] + embv, acc[1] + embv, acc[2] + embv, acc[3] + embv};
                *(f32x4*)(outg + idx) = vst;
            }
        }
        __syncthreads();   // B4: bufA fully read; next staging may overwrite
    }
}

extern "C" void kernel_launch(void* const* d_in, const int* in_sizes, int n_in,
                              void* d_out, int out_size, void* d_ws, size_t ws_size,
                              hipStream_t stream) {
    const float* xg  = (const float*)d_in[0];
    const float* hg  = (const float*)d_in[1];
    const int*   tg  = (const int*)  d_in[2];
    const float* wpg = (const float*)d_in[3];
    const float* bpg = (const float*)d_in[4];
    const float* w1g = (const float*)d_in[5];
    const float* b1g = (const float*)d_in[6];
    const float* w2g = (const float*)d_in[7];
    const float* b2g = (const float*)d_in[8];
    const float* w3g = (const float*)d_in[9];
    const float* wtg = (const float*)d_in[10];
    const float* btg = (const float*)d_in[11];
    float* outg = (float*)d_out;
    short* wsb  = (short*)d_ws;
    float* wsf  = (float*)d_ws + WSF_OFF;

    prep_emb_kernel<<<146, 256, 0, stream>>>(wpg, bpg, w1g, b1g, w2g, b2g, w3g,
                                             tg, wtg, btg, wsb, wsf);
    canet_main<<<4096, 256, 0, stream>>>(xg, hg, wsb, wsf, outg);
}